// Round 10
// baseline (832.405 us; speedup 1.0000x reference)
//
#include <hip/hip_runtime.h>
#include <hip/hip_bf16.h>

// R-GCN 2-layer forward, round-12: FUSED aggregate+GEMM, v2 (correct granularity).
// Round-7's fusion failed from 9 barrier-locked phases with ~2 gathers of work
// each. v2: one WG = 16 nodes, 256 threads, ONE gather phase (16 nodes x 8 rels
// x 2 column-halves = 256 independent per-thread segments, f32 reg accumulate,
// bf16 -> swizzled LDS A-panel [16x1152], 36KB) -> one barrier -> MFMA phase
// (36 K-steps, A from LDS, B from L2-hot Bt). 4 WGs/CU overlap gather||MFMA.
// Kills the ACC round-trip (~300MB HBM-level traffic) + aggregate + gemm.
// Sort (round-10: 1024-thr TILE=4096 scatterA), passB, cast unchanged. No nt.

#define D 128
#define KTOT 1152
#define BSH 9            // log2(coarse bucket size in nodes)
#define BSZ 512          // nodes per coarse bucket
#define TILE 4096        // edges per scatterA WG

typedef __attribute__((ext_vector_type(8))) __bf16 bf16x8;
typedef __attribute__((ext_vector_type(8))) unsigned short us8;
typedef __attribute__((ext_vector_type(4))) unsigned short us4;
typedef __attribute__((ext_vector_type(4))) float f32x4;

__device__ __forceinline__ unsigned short f2bf(float f) {
    union { float f; unsigned u; } v; v.f = f;
    unsigned r = v.u + 0x7FFF + ((v.u >> 16) & 1);   // RNE
    return (unsigned short)(r >> 16);
}
__device__ __forceinline__ float bf2f(unsigned short u) {
    return __uint_as_float((unsigned)u << 16);
}

// Fused LDS A-panel offset (in shorts): 16 rows x 144 chunks(16B) per row.
// chunk = rr*16 + (c4 ^ ((row+rr)&15)): keeps chunk inside slice rr; spreads
// both the 16-row MFMA reads and the per-thread 8-chunk writes across bank
// groups (2-way max = free).
__device__ __forceinline__ int aoff(int row, int rr, int c4) {
    return (row * 144 + rr * 16 + (c4 ^ ((row + rr) & 15))) * 8;
}

// ---------------- sort pass A: coarse-bucket histogram / scan / tile-sorted scatter ----------------

__global__ __launch_bounds__(256) void histA_kernel(const int* __restrict__ dst,
                                                    int* __restrict__ bcnt, int E, int nbuck) {
    __shared__ int c[1024];
    int t = threadIdx.x;
    for (int i = t; i < nbuck; i += 256) c[i] = 0;
    __syncthreads();
    int stride = gridDim.x * 256;
    for (int e = blockIdx.x * 256 + t; e < E; e += stride)
        atomicAdd(&c[dst[e] >> BSH], 1);
    __syncthreads();
    for (int i = t; i < nbuck; i += 256)
        if (c[i]) atomicAdd(&bcnt[i], c[i]);
}

__global__ __launch_bounds__(1024) void scanA_kernel(const int* __restrict__ bcnt,
                                                     int* __restrict__ boffs,
                                                     int* __restrict__ bhead, int nbuck) {
    int t = threadIdx.x;
    int v = (t < nbuck) ? bcnt[t] : 0;
    int lane = t & 63, w = t >> 6;
    int inc = v;
    #pragma unroll
    for (int off = 1; off < 64; off <<= 1) {
        int n = __shfl_up(inc, off, 64);
        if (lane >= off) inc += n;
    }
    __shared__ int ws[16];
    if (lane == 63) ws[w] = inc;
    __syncthreads();
    int wbase = 0;
    for (int i = 0; i < w; ++i) wbase += ws[i];
    int ex = wbase + inc - v;
    if (t < nbuck) { boffs[t] = ex; bhead[t] = ex; }
    if (t == nbuck - 1) boffs[nbuck] = ex + v;
}

__global__ __launch_bounds__(1024) void scatterA_kernel(const int* __restrict__ src,
                                                        const int* __restrict__ dst,
                                                        const int* __restrict__ et,
                                                        int* __restrict__ bhead,
                                                        int* __restrict__ sortedA, int E, int nbuck) {
    __shared__ int skey[TILE];
    __shared__ unsigned char sbkt[TILE];
    __shared__ int cnt[256];
    __shared__ int lpos[256];
    __shared__ int gdelta[256];
    __shared__ int ws[4];
    const int t = threadIdx.x;
    const int e0 = blockIdx.x * TILE;
    int dreg[4];

    if (t < 256) cnt[t] = 0;
    __syncthreads();
    #pragma unroll
    for (int j = 0; j < 4; ++j) {
        int e = e0 + j * 1024 + t;
        int d = -1;
        if (e < E) { d = dst[e]; atomicAdd(&cnt[d >> BSH], 1); }
        dreg[j] = d;
    }
    __syncthreads();
    int c = 0, inc = 0;
    const int lane = t & 63, w = t >> 6;
    if (t < 256) {
        c = cnt[t];
        inc = c;
        #pragma unroll
        for (int off = 1; off < 64; off <<= 1) {
            int n = __shfl_up(inc, off, 64);
            if (lane >= off) inc += n;
        }
        if (lane == 63) ws[w] = inc;
    }
    __syncthreads();
    if (t < 256) {
        int wbase = 0;
        for (int i = 0; i < w; ++i) wbase += ws[i];
        int ex = wbase + inc - c;
        lpos[t] = ex;
        if (c) gdelta[t] = atomicAdd(&bhead[t], c) - ex;
    }
    __syncthreads();
    #pragma unroll
    for (int j = 0; j < 4; ++j) {
        int e = e0 + j * 1024 + t;
        if (e < E) {
            int d = dreg[j];
            int b = d >> BSH;
            int key = ((d & (BSZ - 1)) << 20) | (et[e] << 17) | src[e];
            int p = atomicAdd(&lpos[b], 1);
            skey[p] = key;
            sbkt[p] = (unsigned char)b;
        }
    }
    __syncthreads();
    int ntile = min(TILE, E - e0);
    for (int i = t; i < ntile; i += 1024)
        sortedA[gdelta[sbkt[i]] + i] = skey[i];
}

// ---------------- sort pass B: per-bucket fine sort by (node,rel) -> offs2[] + sorted[] ----------------

__global__ __launch_bounds__(256) void passB_kernel(const int* __restrict__ sortedA,
                                                    const int* __restrict__ boffs,
                                                    int* __restrict__ sorted,
                                                    int* __restrict__ offs2,
                                                    int N8, int E, int nbuck) {
    __shared__ int cnt[4096];
    __shared__ int cur[4096];
    __shared__ int ws[4];
    const int b = blockIdx.x;
    const int t = threadIdx.x;
    const int gb0 = boffs[b], gb1 = boffs[b + 1];
    #pragma unroll
    for (int i = 0; i < 16; ++i) cnt[i * 256 + t] = 0;
    __syncthreads();
    for (int e = gb0 + t; e < gb1; e += 256) {
        int k = sortedA[e];
        atomicAdd(&cnt[(k >> 17) & 4095], 1);   // (dst_low << 3) | etype
    }
    __syncthreads();
    const int base = t * 16;
    int s = 0;
    #pragma unroll
    for (int i = 0; i < 16; ++i) s += cnt[base + i];
    int lane = t & 63, w = t >> 6;
    int inc = s;
    #pragma unroll
    for (int off = 1; off < 64; off <<= 1) {
        int n = __shfl_up(inc, off, 64);
        if (lane >= off) inc += n;
    }
    if (lane == 63) ws[w] = inc;
    __syncthreads();
    int wbase = 0;
    for (int i = 0; i < w; ++i) wbase += ws[i];
    int run = gb0 + wbase + inc - s;
    int g0 = (b << 12) + base;
    #pragma unroll
    for (int i = 0; i < 16; ++i) {
        int cv = cnt[base + i];
        cur[base + i] = run;
        if (g0 + i <= N8) offs2[g0 + i] = run;
        run += cv;
    }
    __syncthreads();
    for (int e = gb0 + t; e < gb1; e += 256) {
        int k = sortedA[e];
        int p = atomicAdd(&cur[(k >> 17) & 4095], 1);
        sorted[p] = k;
    }
}

// ---------------- combined cast: Bt[o][k] bf16 (both layers) + hb0 bf16 ----------------

__global__ void cast_kernel(const float* __restrict__ W1, const float* __restrict__ lw1,
                            const float* __restrict__ W2, const float* __restrict__ lw2,
                            const float* __restrict__ feats,
                            unsigned short* __restrict__ Bt1, unsigned short* __restrict__ Bt2,
                            unsigned short* __restrict__ hb0, int n4) {
    const int per = KTOT * D;          // 147456
    int idx = blockIdx.x * blockDim.x + threadIdx.x;
    if (idx < 2 * per) {
        int layer = idx / per;
        int rem = idx - layer * per;
        int k = rem >> 7;
        int o = rem & 127;             // coalesced read dim
        const float* W  = layer ? W2 : W1;
        const float* lw = layer ? lw2 : lw1;
        float val = (k < 1024) ? W[k * D + o] : lw[(k - 1024) * D + o];
        unsigned short* Bt = layer ? Bt2 : Bt1;
        Bt[o * KTOT + k] = f2bf(val);
    } else {
        int i = idx - 2 * per;
        if (i < n4) {
            float4 v = *(const float4*)(feats + (size_t)i * 4);
            us4 o; o.x = f2bf(v.x); o.y = f2bf(v.y); o.z = f2bf(v.z); o.w = f2bf(v.w);
            *(us4*)(hb0 + (size_t)i * 4) = o;
        }
    }
}

// ---------------- FUSED aggregate + GEMM (v2) ----------------
// WG = 256 thr = 16 node rows. Gather: one (node,rel,col-half) unit per thread,
// f32 reg accumulate (64 floats), one f2bf round, swizzled LDS write. Self-loop
// slice: one 16B chunk per thread. ONE barrier. Then MFMA: 36 K-steps, wave w
// owns cols [w*32, w*32+32), A from LDS, B from L2-hot Bt.

__global__ __launch_bounds__(256, 4) void fused_kernel(const unsigned short* __restrict__ hb,
                                                       const int* __restrict__ offs2,
                                                       const int* __restrict__ sorted,
                                                       const unsigned short* __restrict__ Bt,
                                                       const float* __restrict__ bias,
                                                       float* __restrict__ outf,
                                                       unsigned short* __restrict__ outb,
                                                       int N, int relu_bf) {
    __shared__ unsigned short Asl[16 * 144 * 8];   // 36864 B
    const int t = threadIdx.x;
    const int v0 = blockIdx.x * 16;

    // ---- gather phase: per-thread segment, no sync ----
    {
        const int n = t >> 4;          // node row 0..15
        const int sub = t & 15;
        const int r = sub >> 1;        // relation 0..7
        const int half = sub & 1;      // column half (64 cols)
        const int v = v0 + n;
        int e0 = 0, e1 = 0;
        if (v < N) { e0 = offs2[v * 8 + r]; e1 = offs2[v * 8 + r + 1]; }
        float a[64];
        #pragma unroll
        for (int j = 0; j < 64; ++j) a[j] = 0.f;
        const unsigned short* hbase = hb + half * 64;
        for (int e = e0; e < e1; ++e) {
            int s = sorted[e] & 131071;
            const unsigned short* rowp = hbase + (size_t)s * D;
            #pragma unroll
            for (int c4 = 0; c4 < 8; ++c4) {
                us8 hv = *(const us8*)(rowp + c4 * 8);
                #pragma unroll
                for (int j = 0; j < 8; ++j) a[c4 * 8 + j] += bf2f(hv[j]);
            }
        }
        #pragma unroll
        for (int c4 = 0; c4 < 8; ++c4) {
            us8 o;
            #pragma unroll
            for (int j = 0; j < 8; ++j) o[j] = f2bf(a[c4 * 8 + j]);
            *(us8*)(Asl + aoff(n, r, half * 8 + c4)) = o;
        }
    }
    // self-loop slice (rr=8): one chunk per thread
    {
        const int n = t >> 4;
        const int c4 = t & 15;
        const int v = v0 + n;
        us8 hv = {0, 0, 0, 0, 0, 0, 0, 0};
        if (v < N) hv = *(const us8*)(hb + (size_t)v * D + c4 * 8);
        *(us8*)(Asl + aoff(n, 8, c4)) = hv;
    }
    __syncthreads();

    // ---- MFMA phase ----
    const int lane = t & 63;
    const int w = t >> 6;
    const int quad = lane >> 4;
    const int c16 = lane & 15;
    f32x4 acc[2];
    acc[0] = f32x4{0.f, 0.f, 0.f, 0.f};
    acc[1] = f32x4{0.f, 0.f, 0.f, 0.f};
    const unsigned short* B0 = Bt + (size_t)(w * 32 + c16) * KTOT + quad * 8;
    const unsigned short* B1 = Bt + (size_t)(w * 32 + 16 + c16) * KTOT + quad * 8;

    #pragma unroll
    for (int rr = 0; rr < 9; ++rr) {
        #pragma unroll
        for (int ks = 0; ks < 4; ++ks) {
            bf16x8 af = *(const bf16x8*)(Asl + aoff(c16, rr, ks * 4 + quad));
            const int kb = rr * 128 + ks * 32;
            bf16x8 b0 = *(const bf16x8*)(B0 + kb);
            bf16x8 b1 = *(const bf16x8*)(B1 + kb);
            acc[0] = __builtin_amdgcn_mfma_f32_16x16x32_bf16(af, b0, acc[0], 0, 0, 0);
            acc[1] = __builtin_amdgcn_mfma_f32_16x16x32_bf16(af, b1, acc[1], 0, 0, 0);
        }
    }

    // epilogue: C[row=quad*4+i][col=c16] per 16x16 tile (verified layout)
    int row0 = v0 + quad * 4;
    #pragma unroll
    for (int ct = 0; ct < 2; ++ct) {
        int col = w * 32 + ct * 16 + c16;
        float bcol = bias[col];
        #pragma unroll
        for (int i = 0; i < 4; ++i) {
            int r = row0 + i;
            if (r < N) {
                float vv = acc[ct][i] + bcol;
                if (relu_bf) {
                    vv = fmaxf(vv, 0.f);
                    outb[(size_t)r * D + col] = f2bf(vv);
                } else {
                    outf[(size_t)r * D + col] = vv;
                }
            }
        }
    }
}

// ---------------- launch ----------------

extern "C" void kernel_launch(void* const* d_in, const int* in_sizes, int n_in,
                              void* d_out, int out_size, void* d_ws, size_t ws_size,
                              hipStream_t stream) {
    const float* feats = (const float*)d_in[0];
    const float* W1    = (const float*)d_in[1];
    const float* lw1   = (const float*)d_in[2];
    const float* b1    = (const float*)d_in[3];
    const float* W2    = (const float*)d_in[4];
    const float* lw2   = (const float*)d_in[5];
    const float* b2    = (const float*)d_in[6];
    const int*   src   = (const int*)d_in[7];
    const int*   dst   = (const int*)d_in[8];
    const int*   etype = (const int*)d_in[9];
    const int N = in_sizes[0] / D;
    const int E = in_sizes[7];
    float* out = (float*)d_out;

    const int nbuck = (N + BSZ - 1) >> BSH;

    size_t woff = 0;
    auto take = [&](size_t bytes) -> void* {
        void* p = (char*)d_ws + woff;
        woff += (bytes + 255) & ~(size_t)255;
        return p;
    };
    int* bcnt           = (int*)take((size_t)1024 * 4);
    int* boffs          = (int*)take((size_t)1025 * 4);
    int* bhead          = (int*)take((size_t)1024 * 4);
    int* offs2          = (int*)take((size_t)(N * 8 + 1) * 4);
    int* sortedA        = (int*)take((size_t)E * 4);
    int* sorted         = (int*)take((size_t)E * 4);
    unsigned short* Bt1 = (unsigned short*)take((size_t)KTOT * D * 2);
    unsigned short* Bt2 = (unsigned short*)take((size_t)KTOT * D * 2);
    unsigned short* hb0 = (unsigned short*)take((size_t)N * D * 2);
    unsigned short* hb1 = (unsigned short*)take((size_t)N * D * 2);

    (void)hipMemsetAsync(bcnt, 0, (size_t)nbuck * 4, stream);

    histA_kernel<<<1024, 256, 0, stream>>>(dst, bcnt, E, nbuck);
    scanA_kernel<<<1, 1024, 0, stream>>>(bcnt, boffs, bhead, nbuck);
    scatterA_kernel<<<(E + TILE - 1) / TILE, 1024, 0, stream>>>(src, dst, etype, bhead, sortedA, E, nbuck);
    passB_kernel<<<nbuck, 256, 0, stream>>>(sortedA, boffs, sorted, offs2, N * 8, E, nbuck);

    int n4 = N * D / 4;
    int cb = (2 * KTOT * D + n4 + 255) / 256;
    cast_kernel<<<cb, 256, 0, stream>>>(W1, lw1, W2, lw2, feats, Bt1, Bt2, hb0, n4);

    int fb = (N + 15) / 16;
    fused_kernel<<<fb, 256, 0, stream>>>(hb0, offs2, sorted, Bt1, b1, nullptr, hb1, N, 1);
    fused_kernel<<<fb, 256, 0, stream>>>(hb1, offs2, sorted, Bt2, b2, out, nullptr, N, 0);
}

// Round 11
// 780.752 us; speedup vs baseline: 1.0662x; 1.0662x over previous
//
#include <hip/hip_runtime.h>
#include <hip/hip_bf16.h>

// R-GCN 2-layer forward, round-13: round-10 base (best, 531us) + LDS-FREE gemm.
// Fusion refuted twice (r7: barrier-phased latency; r12: per-thread gather
// destroys line coalescing, FETCH 207MB). Split pipeline kept.
// gemm redesign: no LDS, no barriers. MFMA fragments load DIRECT from global:
//   A: lanes (c16,quad) read 16 rows x full 64B lines (coalesced, read-once)
//   B: 294KB Bt is L2-resident; each wave owns 32 cols x 64 rows (acc[4][2])
//      so each B line is read once per WG. Pure dataflow -> compiler pipelines.
// Sort (1024-thr TILE=4096 scatterA), passB, cast, segment-parallel aggregate
// unchanged from round-10.

#define D 128
#define KTOT 1152
#define KACC 1024
#define BK 32
#define BSH 9            // log2(coarse bucket size in nodes)
#define BSZ 512          // nodes per coarse bucket
#define TILE 4096        // edges per scatterA WG

typedef __attribute__((ext_vector_type(8))) __bf16 bf16x8;
typedef __attribute__((ext_vector_type(8))) unsigned short us8;
typedef __attribute__((ext_vector_type(4))) unsigned short us4;
typedef __attribute__((ext_vector_type(4))) float f32x4;

__device__ __forceinline__ unsigned short f2bf(float f) {
    union { float f; unsigned u; } v; v.f = f;
    unsigned r = v.u + 0x7FFF + ((v.u >> 16) & 1);   // RNE
    return (unsigned short)(r >> 16);
}
__device__ __forceinline__ float bf2f(unsigned short u) {
    return __uint_as_float((unsigned)u << 16);
}

// ---------------- sort pass A: coarse-bucket histogram / scan / tile-sorted scatter ----------------

__global__ __launch_bounds__(256) void histA_kernel(const int* __restrict__ dst,
                                                    int* __restrict__ bcnt, int E, int nbuck) {
    __shared__ int c[1024];
    int t = threadIdx.x;
    for (int i = t; i < nbuck; i += 256) c[i] = 0;
    __syncthreads();
    int stride = gridDim.x * 256;
    for (int e = blockIdx.x * 256 + t; e < E; e += stride)
        atomicAdd(&c[dst[e] >> BSH], 1);
    __syncthreads();
    for (int i = t; i < nbuck; i += 256)
        if (c[i]) atomicAdd(&bcnt[i], c[i]);
}

__global__ __launch_bounds__(1024) void scanA_kernel(const int* __restrict__ bcnt,
                                                     int* __restrict__ boffs,
                                                     int* __restrict__ bhead, int nbuck) {
    int t = threadIdx.x;
    int v = (t < nbuck) ? bcnt[t] : 0;
    int lane = t & 63, w = t >> 6;
    int inc = v;
    #pragma unroll
    for (int off = 1; off < 64; off <<= 1) {
        int n = __shfl_up(inc, off, 64);
        if (lane >= off) inc += n;
    }
    __shared__ int ws[16];
    if (lane == 63) ws[w] = inc;
    __syncthreads();
    int wbase = 0;
    for (int i = 0; i < w; ++i) wbase += ws[i];
    int ex = wbase + inc - v;
    if (t < nbuck) { boffs[t] = ex; bhead[t] = ex; }
    if (t == nbuck - 1) boffs[nbuck] = ex + v;
}

// tile = 4096 edges per WG, 1024 threads (4 edges/thread): LDS counting-sort by
// coarse bucket, then write the reordered tile in per-bucket runs (~21 edges).
__global__ __launch_bounds__(1024) void scatterA_kernel(const int* __restrict__ src,
                                                        const int* __restrict__ dst,
                                                        const int* __restrict__ et,
                                                        int* __restrict__ bhead,
                                                        int* __restrict__ sortedA, int E, int nbuck) {
    __shared__ int skey[TILE];
    __shared__ unsigned char sbkt[TILE];
    __shared__ int cnt[256];
    __shared__ int lpos[256];
    __shared__ int gdelta[256];
    __shared__ int ws[4];
    const int t = threadIdx.x;
    const int e0 = blockIdx.x * TILE;
    int dreg[4];

    if (t < 256) cnt[t] = 0;
    __syncthreads();
    #pragma unroll
    for (int j = 0; j < 4; ++j) {
        int e = e0 + j * 1024 + t;
        int d = -1;
        if (e < E) { d = dst[e]; atomicAdd(&cnt[d >> BSH], 1); }
        dreg[j] = d;
    }
    __syncthreads();
    int c = 0, inc = 0;
    const int lane = t & 63, w = t >> 6;
    if (t < 256) {
        c = cnt[t];
        inc = c;
        #pragma unroll
        for (int off = 1; off < 64; off <<= 1) {
            int n = __shfl_up(inc, off, 64);
            if (lane >= off) inc += n;
        }
        if (lane == 63) ws[w] = inc;
    }
    __syncthreads();
    if (t < 256) {
        int wbase = 0;
        for (int i = 0; i < w; ++i) wbase += ws[i];
        int ex = wbase + inc - c;
        lpos[t] = ex;
        if (c) gdelta[t] = atomicAdd(&bhead[t], c) - ex;
    }
    __syncthreads();
    #pragma unroll
    for (int j = 0; j < 4; ++j) {
        int e = e0 + j * 1024 + t;
        if (e < E) {
            int d = dreg[j];
            int b = d >> BSH;
            int key = ((d & (BSZ - 1)) << 20) | (et[e] << 17) | src[e];
            int p = atomicAdd(&lpos[b], 1);
            skey[p] = key;
            sbkt[p] = (unsigned char)b;
        }
    }
    __syncthreads();
    int ntile = min(TILE, E - e0);
    for (int i = t; i < ntile; i += 1024)
        sortedA[gdelta[sbkt[i]] + i] = skey[i];
}

// ---------------- sort pass B: per-bucket fine sort by (node,rel) -> offs2[] + sorted[] ----------------

__global__ __launch_bounds__(256) void passB_kernel(const int* __restrict__ sortedA,
                                                    const int* __restrict__ boffs,
                                                    int* __restrict__ sorted,
                                                    int* __restrict__ offs2,
                                                    int N8, int E, int nbuck) {
    __shared__ int cnt[4096];
    __shared__ int cur[4096];
    __shared__ int ws[4];
    const int b = blockIdx.x;
    const int t = threadIdx.x;
    const int gb0 = boffs[b], gb1 = boffs[b + 1];
    #pragma unroll
    for (int i = 0; i < 16; ++i) cnt[i * 256 + t] = 0;
    __syncthreads();
    for (int e = gb0 + t; e < gb1; e += 256) {
        int k = sortedA[e];
        atomicAdd(&cnt[(k >> 17) & 4095], 1);   // (dst_low << 3) | etype
    }
    __syncthreads();
    const int base = t * 16;
    int s = 0;
    #pragma unroll
    for (int i = 0; i < 16; ++i) s += cnt[base + i];
    int lane = t & 63, w = t >> 6;
    int inc = s;
    #pragma unroll
    for (int off = 1; off < 64; off <<= 1) {
        int n = __shfl_up(inc, off, 64);
        if (lane >= off) inc += n;
    }
    if (lane == 63) ws[w] = inc;
    __syncthreads();
    int wbase = 0;
    for (int i = 0; i < w; ++i) wbase += ws[i];
    int run = gb0 + wbase + inc - s;
    int g0 = (b << 12) + base;
    #pragma unroll
    for (int i = 0; i < 16; ++i) {
        int cv = cnt[base + i];
        cur[base + i] = run;
        if (g0 + i <= N8) offs2[g0 + i] = run;
        run += cv;
    }
    __syncthreads();
    // final scatter: all writes land inside this bucket's ~32KB window (L2-hot) -> no amplification
    for (int e = gb0 + t; e < gb1; e += 256) {
        int k = sortedA[e];
        int p = atomicAdd(&cur[(k >> 17) & 4095], 1);
        sorted[p] = k;
    }
}

// ---------------- combined cast: Bt[o][k] bf16 (both layers) + hb0 bf16 ----------------

__global__ void cast_kernel(const float* __restrict__ W1, const float* __restrict__ lw1,
                            const float* __restrict__ W2, const float* __restrict__ lw2,
                            const float* __restrict__ feats,
                            unsigned short* __restrict__ Bt1, unsigned short* __restrict__ Bt2,
                            unsigned short* __restrict__ hb0, int n4) {
    const int per = KTOT * D;          // 147456
    int idx = blockIdx.x * blockDim.x + threadIdx.x;
    if (idx < 2 * per) {
        int layer = idx / per;
        int rem = idx - layer * per;
        int k = rem >> 7;
        int o = rem & 127;             // coalesced read dim
        const float* W  = layer ? W2 : W1;
        const float* lw = layer ? lw2 : lw1;
        float val = (k < 1024) ? W[k * D + o] : lw[(k - 1024) * D + o];
        unsigned short* Bt = layer ? Bt2 : Bt1;
        Bt[o * KTOT + k] = f2bf(val);
    } else {
        int i = idx - 2 * per;
        if (i < n4) {
            float4 v = *(const float4*)(feats + (size_t)i * 4);
            us4 o; o.x = f2bf(v.x); o.y = f2bf(v.y); o.z = f2bf(v.z); o.w = f2bf(v.w);
            *(us4*)(hb0 + (size_t)i * 4) = o;
        }
    }
}

// ---------------- aggregation: one (node,rel) SEGMENT per 16-lane unit ----------------

__global__ __launch_bounds__(256) void aggregate_kernel(const unsigned short* __restrict__ hb,
                                                        const int* __restrict__ offs2,
                                                        const int* __restrict__ sorted,
                                                        unsigned short* __restrict__ A,
                                                        int v0, int vend) {
    const int t = threadIdx.x;
    const int c = (t & 15) * 8;            // 8 bf16 cols per lane
    const int gu = blockIdx.x * 16 + (t >> 4);
    const int v = v0 + (gu >> 3);
    const int r = gu & 7;
    if (v >= vend) return;

    const int e0 = offs2[v * 8 + r];
    const int e1 = offs2[v * 8 + r + 1];

    float a0[8], a1[8];
    #pragma unroll
    for (int j = 0; j < 8; ++j) { a0[j] = 0.f; a1[j] = 0.f; }

    int e = e0;
    for (; e + 1 < e1; e += 2) {
        int p0 = sorted[e], p1 = sorted[e + 1];
        us8 h0 = *(const us8*)(hb + (size_t)(p0 & 131071) * D + c);
        us8 h1 = *(const us8*)(hb + (size_t)(p1 & 131071) * D + c);
        #pragma unroll
        for (int j = 0; j < 8; ++j) { a0[j] += bf2f(h0[j]); a1[j] += bf2f(h1[j]); }
    }
    if (e < e1) {
        int p0 = sorted[e];
        us8 h0 = *(const us8*)(hb + (size_t)(p0 & 131071) * D + c);
        #pragma unroll
        for (int j = 0; j < 8; ++j) a0[j] += bf2f(h0[j]);
    }

    us8 o;
    #pragma unroll
    for (int j = 0; j < 8; ++j) o[j] = f2bf(a0[j] + a1[j]);
    *(us8*)(A + (size_t)(v - v0) * KACC + r * 128 + c) = o;
}

// ---------------- GEMM: out[v0:vend][128] = [ACC | hb_self] @ Bt^T + bias (+ReLU) ----------------
// LDS-free, barrier-free. WG = 256 thr = 64 rows; wave w owns cols
// [w*32, w*32+32) x all 64 rows (acc[4][2]). A-fragments direct from global
// (16 rows x full 64B lines per instr, read-once); B direct from L2-hot Bt
// (each line read once per WG). Tail rows: clamp A-row pointer (garbage only
// reaches epilogue-masked rows).

__global__ __launch_bounds__(256) void gemm_kernel(const unsigned short* __restrict__ A,
                                                   const unsigned short* __restrict__ hbA,
                                                   const unsigned short* __restrict__ Bt,
                                                   const float* __restrict__ bias,
                                                   float* __restrict__ outf,
                                                   unsigned short* __restrict__ outb,
                                                   int v0, int vend, int relu_bf) {
    const int t = threadIdx.x;
    const int lane = t & 63;
    const int w = t >> 6;              // wave owns cols [w*32, w*32+32)
    const int quad = lane >> 4;
    const int c16 = lane & 15;
    const int blockRow0 = v0 + blockIdx.x * 64;

    f32x4 acc[4][2];
    #pragma unroll
    for (int rg = 0; rg < 4; ++rg) {
        acc[rg][0] = f32x4{0.f, 0.f, 0.f, 0.f};
        acc[rg][1] = f32x4{0.f, 0.f, 0.f, 0.f};
    }

    const unsigned short* Ap0; const unsigned short* Ap1;
    const unsigned short* Ap2; const unsigned short* Ap3;
    const unsigned short* Hp0; const unsigned short* Hp1;
    const unsigned short* Hp2; const unsigned short* Hp3;
    {
        int r0 = min(blockRow0 +  0 + c16, vend - 1);
        int r1 = min(blockRow0 + 16 + c16, vend - 1);
        int r2 = min(blockRow0 + 32 + c16, vend - 1);
        int r3 = min(blockRow0 + 48 + c16, vend - 1);
        Ap0 = A + (size_t)(r0 - v0) * KACC + quad * 8;
        Ap1 = A + (size_t)(r1 - v0) * KACC + quad * 8;
        Ap2 = A + (size_t)(r2 - v0) * KACC + quad * 8;
        Ap3 = A + (size_t)(r3 - v0) * KACC + quad * 8;
        Hp0 = hbA + (size_t)r0 * D + quad * 8;
        Hp1 = hbA + (size_t)r1 * D + quad * 8;
        Hp2 = hbA + (size_t)r2 * D + quad * 8;
        Hp3 = hbA + (size_t)r3 * D + quad * 8;
    }
    const unsigned short* Bp0 = Bt + (size_t)(w * 32 + c16) * KTOT + quad * 8;
    const unsigned short* Bp1 = Bt + (size_t)(w * 32 + 16 + c16) * KTOT + quad * 8;

    #pragma unroll 4
    for (int k0 = 0; k0 < KACC; k0 += BK) {
        bf16x8 b0 = *(const bf16x8*)(Bp0 + k0);
        bf16x8 b1 = *(const bf16x8*)(Bp1 + k0);
        bf16x8 a0 = *(const bf16x8*)(Ap0 + k0);
        bf16x8 a1 = *(const bf16x8*)(Ap1 + k0);
        bf16x8 a2 = *(const bf16x8*)(Ap2 + k0);
        bf16x8 a3 = *(const bf16x8*)(Ap3 + k0);
        acc[0][0] = __builtin_amdgcn_mfma_f32_16x16x32_bf16(a0, b0, acc[0][0], 0, 0, 0);
        acc[0][1] = __builtin_amdgcn_mfma_f32_16x16x32_bf16(a0, b1, acc[0][1], 0, 0, 0);
        acc[1][0] = __builtin_amdgcn_mfma_f32_16x16x32_bf16(a1, b0, acc[1][0], 0, 0, 0);
        acc[1][1] = __builtin_amdgcn_mfma_f32_16x16x32_bf16(a1, b1, acc[1][1], 0, 0, 0);
        acc[2][0] = __builtin_amdgcn_mfma_f32_16x16x32_bf16(a2, b0, acc[2][0], 0, 0, 0);
        acc[2][1] = __builtin_amdgcn_mfma_f32_16x16x32_bf16(a2, b1, acc[2][1], 0, 0, 0);
        acc[3][0] = __builtin_amdgcn_mfma_f32_16x16x32_bf16(a3, b0, acc[3][0], 0, 0, 0);
        acc[3][1] = __builtin_amdgcn_mfma_f32_16x16x32_bf16(a3, b1, acc[3][1], 0, 0, 0);
    }
    #pragma unroll
    for (int k0 = 0; k0 < D; k0 += BK) {   // self-loop K-slice from feature table
        bf16x8 b0 = *(const bf16x8*)(Bp0 + KACC + k0);
        bf16x8 b1 = *(const bf16x8*)(Bp1 + KACC + k0);
        bf16x8 a0 = *(const bf16x8*)(Hp0 + k0);
        bf16x8 a1 = *(const bf16x8*)(Hp1 + k0);
        bf16x8 a2 = *(const bf16x8*)(Hp2 + k0);
        bf16x8 a3 = *(const bf16x8*)(Hp3 + k0);
        acc[0][0] = __builtin_amdgcn_mfma_f32_16x16x32_bf16(a0, b0, acc[0][0], 0, 0, 0);
        acc[0][1] = __builtin_amdgcn_mfma_f32_16x16x32_bf16(a0, b1, acc[0][1], 0, 0, 0);
        acc[1][0] = __builtin_amdgcn_mfma_f32_16x16x32_bf16(a1, b0, acc[1][0], 0, 0, 0);
        acc[1][1] = __builtin_amdgcn_mfma_f32_16x16x32_bf16(a1, b1, acc[1][1], 0, 0, 0);
        acc[2][0] = __builtin_amdgcn_mfma_f32_16x16x32_bf16(a2, b0, acc[2][0], 0, 0, 0);
        acc[2][1] = __builtin_amdgcn_mfma_f32_16x16x32_bf16(a2, b1, acc[2][1], 0, 0, 0);
        acc[3][0] = __builtin_amdgcn_mfma_f32_16x16x32_bf16(a3, b0, acc[3][0], 0, 0, 0);
        acc[3][1] = __builtin_amdgcn_mfma_f32_16x16x32_bf16(a3, b1, acc[3][1], 0, 0, 0);
    }

    // epilogue: C[row = rg*16 + quad*4 + i][col = w*32 + ct*16 + c16]
    #pragma unroll
    for (int rg = 0; rg < 4; ++rg) {
        int row = blockRow0 + rg * 16 + quad * 4;
        #pragma unroll
        for (int ct = 0; ct < 2; ++ct) {
            int col = w * 32 + ct * 16 + c16;
            float bcol = bias[col];
            #pragma unroll
            for (int i = 0; i < 4; ++i) {
                int r = row + i;
                if (r < vend) {
                    float vv = acc[rg][ct][i] + bcol;
                    if (relu_bf) {
                        vv = fmaxf(vv, 0.f);
                        outb[(size_t)r * D + col] = f2bf(vv);
                    } else {
                        outf[(size_t)r * D + col] = vv;
                    }
                }
            }
        }
    }
}

// ---------------- launch ----------------

extern "C" void kernel_launch(void* const* d_in, const int* in_sizes, int n_in,
                              void* d_out, int out_size, void* d_ws, size_t ws_size,
                              hipStream_t stream) {
    const float* feats = (const float*)d_in[0];
    const float* W1    = (const float*)d_in[1];
    const float* lw1   = (const float*)d_in[2];
    const float* b1    = (const float*)d_in[3];
    const float* W2    = (const float*)d_in[4];
    const float* lw2   = (const float*)d_in[5];
    const float* b2    = (const float*)d_in[6];
    const int*   src   = (const int*)d_in[7];
    const int*   dst   = (const int*)d_in[8];
    const int*   etype = (const int*)d_in[9];
    const int N = in_sizes[0] / D;
    const int E = in_sizes[7];
    float* out = (float*)d_out;

    const int ch = (N + 1) / 2;           // node chunk size (2 chunks)
    const int nbuck = (N + BSZ - 1) >> BSH;

    size_t woff = 0;
    auto take = [&](size_t bytes) -> void* {
        void* p = (char*)d_ws + woff;
        woff += (bytes + 255) & ~(size_t)255;
        return p;
    };
    int* bcnt           = (int*)take((size_t)1024 * 4);
    int* boffs          = (int*)take((size_t)1025 * 4);
    int* bhead          = (int*)take((size_t)1024 * 4);
    int* offs2          = (int*)take((size_t)(N * 8 + 1) * 4);
    int* sortedA        = (int*)take((size_t)E * 4);
    int* sorted         = (int*)take((size_t)E * 4);
    unsigned short* Bt1 = (unsigned short*)take((size_t)KTOT * D * 2);
    unsigned short* Bt2 = (unsigned short*)take((size_t)KTOT * D * 2);
    unsigned short* hb0 = (unsigned short*)take((size_t)N * D * 2);
    unsigned short* hb1 = (unsigned short*)take((size_t)N * D * 2);
    unsigned short* ACC = (unsigned short*)take((size_t)ch * KACC * 2);   // ~102 MB

    (void)hipMemsetAsync(bcnt, 0, (size_t)nbuck * 4, stream);

    histA_kernel<<<1024, 256, 0, stream>>>(dst, bcnt, E, nbuck);
    scanA_kernel<<<1, 1024, 0, stream>>>(bcnt, boffs, bhead, nbuck);
    scatterA_kernel<<<(E + TILE - 1) / TILE, 1024, 0, stream>>>(src, dst, etype, bhead, sortedA, E, nbuck);
    passB_kernel<<<nbuck, 256, 0, stream>>>(sortedA, boffs, sorted, offs2, N * 8, E, nbuck);

    int n4 = N * D / 4;
    int cb = (2 * KTOT * D + n4 + 255) / 256;
    cast_kernel<<<cb, 256, 0, stream>>>(W1, lw1, W2, lw2, feats, Bt1, Bt2, hb0, n4);

    for (int layer = 0; layer < 2; ++layer) {
        const unsigned short* hin = layer ? hb1 : hb0;
        const unsigned short* Bt  = layer ? Bt2 : Bt1;
        const float* bias         = layer ? b2  : b1;
        for (int c0 = 0; c0 < N; c0 += ch) {
            int c1 = (c0 + ch < N) ? (c0 + ch) : N;
            int len = c1 - c0;
            int ab = (len * 8 + 15) / 16;   // one (node,rel) segment per 16-lane unit
            int gb = (len + 63) / 64;
            aggregate_kernel<<<ab, 256, 0, stream>>>(hin, offs2, sorted, ACC, c0, c1);
            gemm_kernel<<<gb, 256, 0, stream>>>(ACC, hin, Bt, bias, out, hb1, c0, c1, 1 - layer);
        }
    }
}

// Round 12
// 586.859 us; speedup vs baseline: 1.4184x; 1.3304x over previous
//
#include <hip/hip_runtime.h>
#include <hip/hip_bf16.h>

// R-GCN 2-layer forward, round-14: round-10 base (best, 531us) with gemm
// BM 64->32 inside the PROVEN LDS+prefetch structure (round-13's LDS-free
// variant refuted: no inter-wave sharing -> 106us). BM=32 -> 1563 WGs/dispatch
// = 6 WG/CU, ~24 waves/CU resident (LDS only 10KB/WG) -> latency hiding for
// the A-stream. A-staging by threads t<128; B staging/pipeline unchanged.
// Sort (1024-thr TILE=4096 scatterA), passB, cast, segment-parallel aggregate
// identical to round-10.

#define D 128
#define KTOT 1152
#define KACC 1024
#define BK 32
#define BSH 9            // log2(coarse bucket size in nodes)
#define BSZ 512          // nodes per coarse bucket
#define TILE 4096        // edges per scatterA WG

typedef __attribute__((ext_vector_type(8))) __bf16 bf16x8;
typedef __attribute__((ext_vector_type(8))) unsigned short us8;
typedef __attribute__((ext_vector_type(4))) unsigned short us4;
typedef __attribute__((ext_vector_type(4))) float f32x4;

__device__ __forceinline__ unsigned short f2bf(float f) {
    union { float f; unsigned u; } v; v.f = f;
    unsigned r = v.u + 0x7FFF + ((v.u >> 16) & 1);   // RNE
    return (unsigned short)(r >> 16);
}
__device__ __forceinline__ float bf2f(unsigned short u) {
    return __uint_as_float((unsigned)u << 16);
}

__device__ __forceinline__ int lds_off(int row, int c) {
    return row * 32 + ((c ^ ((row >> 1) & 3)) << 3);
}

// ---------------- sort pass A: coarse-bucket histogram / scan / tile-sorted scatter ----------------

__global__ __launch_bounds__(256) void histA_kernel(const int* __restrict__ dst,
                                                    int* __restrict__ bcnt, int E, int nbuck) {
    __shared__ int c[1024];
    int t = threadIdx.x;
    for (int i = t; i < nbuck; i += 256) c[i] = 0;
    __syncthreads();
    int stride = gridDim.x * 256;
    for (int e = blockIdx.x * 256 + t; e < E; e += stride)
        atomicAdd(&c[dst[e] >> BSH], 1);
    __syncthreads();
    for (int i = t; i < nbuck; i += 256)
        if (c[i]) atomicAdd(&bcnt[i], c[i]);
}

__global__ __launch_bounds__(1024) void scanA_kernel(const int* __restrict__ bcnt,
                                                     int* __restrict__ boffs,
                                                     int* __restrict__ bhead, int nbuck) {
    int t = threadIdx.x;
    int v = (t < nbuck) ? bcnt[t] : 0;
    int lane = t & 63, w = t >> 6;
    int inc = v;
    #pragma unroll
    for (int off = 1; off < 64; off <<= 1) {
        int n = __shfl_up(inc, off, 64);
        if (lane >= off) inc += n;
    }
    __shared__ int ws[16];
    if (lane == 63) ws[w] = inc;
    __syncthreads();
    int wbase = 0;
    for (int i = 0; i < w; ++i) wbase += ws[i];
    int ex = wbase + inc - v;
    if (t < nbuck) { boffs[t] = ex; bhead[t] = ex; }
    if (t == nbuck - 1) boffs[nbuck] = ex + v;
}

// tile = 4096 edges per WG, 1024 threads (4 edges/thread): LDS counting-sort by
// coarse bucket, then write the reordered tile in per-bucket runs (~21 edges).
__global__ __launch_bounds__(1024) void scatterA_kernel(const int* __restrict__ src,
                                                        const int* __restrict__ dst,
                                                        const int* __restrict__ et,
                                                        int* __restrict__ bhead,
                                                        int* __restrict__ sortedA, int E, int nbuck) {
    __shared__ int skey[TILE];
    __shared__ unsigned char sbkt[TILE];
    __shared__ int cnt[256];
    __shared__ int lpos[256];
    __shared__ int gdelta[256];
    __shared__ int ws[4];
    const int t = threadIdx.x;
    const int e0 = blockIdx.x * TILE;
    int dreg[4];

    if (t < 256) cnt[t] = 0;
    __syncthreads();
    #pragma unroll
    for (int j = 0; j < 4; ++j) {
        int e = e0 + j * 1024 + t;
        int d = -1;
        if (e < E) { d = dst[e]; atomicAdd(&cnt[d >> BSH], 1); }
        dreg[j] = d;
    }
    __syncthreads();
    int c = 0, inc = 0;
    const int lane = t & 63, w = t >> 6;
    if (t < 256) {
        c = cnt[t];
        inc = c;
        #pragma unroll
        for (int off = 1; off < 64; off <<= 1) {
            int n = __shfl_up(inc, off, 64);
            if (lane >= off) inc += n;
        }
        if (lane == 63) ws[w] = inc;
    }
    __syncthreads();
    if (t < 256) {
        int wbase = 0;
        for (int i = 0; i < w; ++i) wbase += ws[i];
        int ex = wbase + inc - c;
        lpos[t] = ex;
        if (c) gdelta[t] = atomicAdd(&bhead[t], c) - ex;
    }
    __syncthreads();
    #pragma unroll
    for (int j = 0; j < 4; ++j) {
        int e = e0 + j * 1024 + t;
        if (e < E) {
            int d = dreg[j];
            int b = d >> BSH;
            int key = ((d & (BSZ - 1)) << 20) | (et[e] << 17) | src[e];
            int p = atomicAdd(&lpos[b], 1);
            skey[p] = key;
            sbkt[p] = (unsigned char)b;
        }
    }
    __syncthreads();
    int ntile = min(TILE, E - e0);
    for (int i = t; i < ntile; i += 1024)
        sortedA[gdelta[sbkt[i]] + i] = skey[i];
}

// ---------------- sort pass B: per-bucket fine sort by (node,rel) -> offs2[] + sorted[] ----------------

__global__ __launch_bounds__(256) void passB_kernel(const int* __restrict__ sortedA,
                                                    const int* __restrict__ boffs,
                                                    int* __restrict__ sorted,
                                                    int* __restrict__ offs2,
                                                    int N8, int E, int nbuck) {
    __shared__ int cnt[4096];
    __shared__ int cur[4096];
    __shared__ int ws[4];
    const int b = blockIdx.x;
    const int t = threadIdx.x;
    const int gb0 = boffs[b], gb1 = boffs[b + 1];
    #pragma unroll
    for (int i = 0; i < 16; ++i) cnt[i * 256 + t] = 0;
    __syncthreads();
    for (int e = gb0 + t; e < gb1; e += 256) {
        int k = sortedA[e];
        atomicAdd(&cnt[(k >> 17) & 4095], 1);   // (dst_low << 3) | etype
    }
    __syncthreads();
    const int base = t * 16;
    int s = 0;
    #pragma unroll
    for (int i = 0; i < 16; ++i) s += cnt[base + i];
    int lane = t & 63, w = t >> 6;
    int inc = s;
    #pragma unroll
    for (int off = 1; off < 64; off <<= 1) {
        int n = __shfl_up(inc, off, 64);
        if (lane >= off) inc += n;
    }
    if (lane == 63) ws[w] = inc;
    __syncthreads();
    int wbase = 0;
    for (int i = 0; i < w; ++i) wbase += ws[i];
    int run = gb0 + wbase + inc - s;
    int g0 = (b << 12) + base;
    #pragma unroll
    for (int i = 0; i < 16; ++i) {
        int cv = cnt[base + i];
        cur[base + i] = run;
        if (g0 + i <= N8) offs2[g0 + i] = run;
        run += cv;
    }
    __syncthreads();
    // final scatter: all writes land inside this bucket's ~32KB window (L2-hot) -> no amplification
    for (int e = gb0 + t; e < gb1; e += 256) {
        int k = sortedA[e];
        int p = atomicAdd(&cur[(k >> 17) & 4095], 1);
        sorted[p] = k;
    }
}

// ---------------- combined cast: Bt[o][k] bf16 (both layers) + hb0 bf16 ----------------

__global__ void cast_kernel(const float* __restrict__ W1, const float* __restrict__ lw1,
                            const float* __restrict__ W2, const float* __restrict__ lw2,
                            const float* __restrict__ feats,
                            unsigned short* __restrict__ Bt1, unsigned short* __restrict__ Bt2,
                            unsigned short* __restrict__ hb0, int n4) {
    const int per = KTOT * D;          // 147456
    int idx = blockIdx.x * blockDim.x + threadIdx.x;
    if (idx < 2 * per) {
        int layer = idx / per;
        int rem = idx - layer * per;
        int k = rem >> 7;
        int o = rem & 127;             // coalesced read dim
        const float* W  = layer ? W2 : W1;
        const float* lw = layer ? lw2 : lw1;
        float val = (k < 1024) ? W[k * D + o] : lw[(k - 1024) * D + o];
        unsigned short* Bt = layer ? Bt2 : Bt1;
        Bt[o * KTOT + k] = f2bf(val);
    } else {
        int i = idx - 2 * per;
        if (i < n4) {
            float4 v = *(const float4*)(feats + (size_t)i * 4);
            us4 o; o.x = f2bf(v.x); o.y = f2bf(v.y); o.z = f2bf(v.z); o.w = f2bf(v.w);
            *(us4*)(hb0 + (size_t)i * 4) = o;
        }
    }
}

// ---------------- aggregation: one (node,rel) SEGMENT per 16-lane unit ----------------

__global__ __launch_bounds__(256) void aggregate_kernel(const unsigned short* __restrict__ hb,
                                                        const int* __restrict__ offs2,
                                                        const int* __restrict__ sorted,
                                                        unsigned short* __restrict__ A,
                                                        int v0, int vend) {
    const int t = threadIdx.x;
    const int c = (t & 15) * 8;            // 8 bf16 cols per lane
    const int gu = blockIdx.x * 16 + (t >> 4);
    const int v = v0 + (gu >> 3);
    const int r = gu & 7;
    if (v >= vend) return;

    const int e0 = offs2[v * 8 + r];
    const int e1 = offs2[v * 8 + r + 1];

    float a0[8], a1[8];
    #pragma unroll
    for (int j = 0; j < 8; ++j) { a0[j] = 0.f; a1[j] = 0.f; }

    int e = e0;
    for (; e + 1 < e1; e += 2) {
        int p0 = sorted[e], p1 = sorted[e + 1];
        us8 h0 = *(const us8*)(hb + (size_t)(p0 & 131071) * D + c);
        us8 h1 = *(const us8*)(hb + (size_t)(p1 & 131071) * D + c);
        #pragma unroll
        for (int j = 0; j < 8; ++j) { a0[j] += bf2f(h0[j]); a1[j] += bf2f(h1[j]); }
    }
    if (e < e1) {
        int p0 = sorted[e];
        us8 h0 = *(const us8*)(hb + (size_t)(p0 & 131071) * D + c);
        #pragma unroll
        for (int j = 0; j < 8; ++j) a0[j] += bf2f(h0[j]);
    }

    us8 o;
    #pragma unroll
    for (int j = 0; j < 8; ++j) o[j] = f2bf(a0[j] + a1[j]);
    *(us8*)(A + (size_t)(v - v0) * KACC + r * 128 + c) = o;
}

// ---------------- GEMM: out[v0:vend][128] = [ACC | hb_self] @ Bt^T + bias (+ReLU) ----------------
// BM=32 (1563 WGs/chunk = 6 WG/CU), LDS 10KB, register prefetch distance 1.
// A staged by threads t<128; B staged by all (same as round-6). Wave w owns
// cols [w*32, w*32+32) x 32 rows -> acc[2][2].

__global__ __launch_bounds__(256) void gemm_kernel(const unsigned short* __restrict__ A,
                                                   const unsigned short* __restrict__ hbA,
                                                   const unsigned short* __restrict__ Bt,
                                                   const float* __restrict__ bias,
                                                   float* __restrict__ outf,
                                                   unsigned short* __restrict__ outb,
                                                   int v0, int vend, int relu_bf) {
    __shared__ unsigned short Alds[32 * 32];
    __shared__ unsigned short Blds[128 * 32];
    const int t = threadIdx.x;
    const int lane = t & 63;
    const int w = t >> 6;
    const int quad = lane >> 4;
    const int c16 = lane & 15;
    const int blockRow0 = v0 + blockIdx.x * 32;

    const int srow = t >> 2;           // 0..63
    const int schunk = t & 3;

    f32x4 acc[2][2];
    #pragma unroll
    for (int i = 0; i < 2; ++i)
        #pragma unroll
        for (int j = 0; j < 2; ++j) acc[i][j] = f32x4{0.f, 0.f, 0.f, 0.f};

    const bool doA = (t < 128);        // A tile 32 rows x 4 chunks
    const int aRow = blockRow0 + srow; // valid only for doA (srow 0..31)
    const bool aval = doA && (aRow < vend);
    const us8 zz = {0, 0, 0, 0, 0, 0, 0, 0};
    const unsigned short* Arow = A + (size_t)(aRow - v0) * KACC + schunk * 8;
    const unsigned short* Hrow = hbA + (size_t)aRow * D + schunk * 8;
    const unsigned short* Brow0 = Bt + (size_t)srow * KTOT + schunk * 8;
    const unsigned short* Brow1 = Bt + (size_t)(srow + 64) * KTOT + schunk * 8;

    // prologue: prefetch K-step 0
    us8 av = zz;
    if (aval) av = *(const us8*)(Arow);
    us8 bv0 = *(const us8*)(Brow0);
    us8 bv1 = *(const us8*)(Brow1);

    for (int k0 = 0; k0 < KTOT; k0 += BK) {
        us8 na = zz, nb0 = zz, nb1 = zz;
        const int kn = k0 + BK;
        if (kn < KTOT) {
            if (aval) {
                if (kn < KACC) na = *(const us8*)(Arow + kn);
                else           na = *(const us8*)(Hrow + (kn - KACC));
            }
            nb0 = *(const us8*)(Brow0 + kn);
            nb1 = *(const us8*)(Brow1 + kn);
        }
        __syncthreads();
        if (doA) *(us8*)(Alds + lds_off(srow, schunk)) = av;
        *(us8*)(Blds + lds_off(srow,      schunk)) = bv0;
        *(us8*)(Blds + lds_off(srow + 64, schunk)) = bv1;
        __syncthreads();

        bf16x8 af[2];
        #pragma unroll
        for (int rt = 0; rt < 2; ++rt)
            af[rt] = *(const bf16x8*)(Alds + lds_off(rt * 16 + c16, quad));
        #pragma unroll
        for (int ct = 0; ct < 2; ++ct) {
            bf16x8 bfr = *(const bf16x8*)(Blds + lds_off(w * 32 + ct * 16 + c16, quad));
            acc[0][ct] = __builtin_amdgcn_mfma_f32_16x16x32_bf16(af[0], bfr, acc[0][ct], 0, 0, 0);
            acc[1][ct] = __builtin_amdgcn_mfma_f32_16x16x32_bf16(af[1], bfr, acc[1][ct], 0, 0, 0);
        }
        av = na; bv0 = nb0; bv1 = nb1;
    }

    // epilogue: C[row = rt*16 + quad*4 + i][col = w*32 + ct*16 + c16]
    #pragma unroll
    for (int rt = 0; rt < 2; ++rt) {
        int row = blockRow0 + rt * 16 + quad * 4;
        #pragma unroll
        for (int ct = 0; ct < 2; ++ct) {
            int col = w * 32 + ct * 16 + c16;
            float bcol = bias[col];
            #pragma unroll
            for (int i = 0; i < 4; ++i) {
                int r = row + i;
                if (r < vend) {
                    float vv = acc[rt][ct][i] + bcol;
                    if (relu_bf) {
                        vv = fmaxf(vv, 0.f);
                        outb[(size_t)r * D + col] = f2bf(vv);
                    } else {
                        outf[(size_t)r * D + col] = vv;
                    }
                }
            }
        }
    }
}

// ---------------- launch ----------------

extern "C" void kernel_launch(void* const* d_in, const int* in_sizes, int n_in,
                              void* d_out, int out_size, void* d_ws, size_t ws_size,
                              hipStream_t stream) {
    const float* feats = (const float*)d_in[0];
    const float* W1    = (const float*)d_in[1];
    const float* lw1   = (const float*)d_in[2];
    const float* b1    = (const float*)d_in[3];
    const float* W2    = (const float*)d_in[4];
    const float* lw2   = (const float*)d_in[5];
    const float* b2    = (const float*)d_in[6];
    const int*   src   = (const int*)d_in[7];
    const int*   dst   = (const int*)d_in[8];
    const int*   etype = (const int*)d_in[9];
    const int N = in_sizes[0] / D;
    const int E = in_sizes[7];
    float* out = (float*)d_out;

    const int ch = (N + 1) / 2;           // node chunk size (2 chunks)
    const int nbuck = (N + BSZ - 1) >> BSH;

    size_t woff = 0;
    auto take = [&](size_t bytes) -> void* {
        void* p = (char*)d_ws + woff;
        woff += (bytes + 255) & ~(size_t)255;
        return p;
    };
    int* bcnt           = (int*)take((size_t)1024 * 4);
    int* boffs          = (int*)take((size_t)1025 * 4);
    int* bhead          = (int*)take((size_t)1024 * 4);
    int* offs2          = (int*)take((size_t)(N * 8 + 1) * 4);
    int* sortedA        = (int*)take((size_t)E * 4);
    int* sorted         = (int*)take((size_t)E * 4);
    unsigned short* Bt1 = (unsigned short*)take((size_t)KTOT * D * 2);
    unsigned short* Bt2 = (unsigned short*)take((size_t)KTOT * D * 2);
    unsigned short* hb0 = (unsigned short*)take((size_t)N * D * 2);
    unsigned short* hb1 = (unsigned short*)take((size_t)N * D * 2);
    unsigned short* ACC = (unsigned short*)take((size_t)ch * KACC * 2);   // ~102 MB

    (void)hipMemsetAsync(bcnt, 0, (size_t)nbuck * 4, stream);

    histA_kernel<<<1024, 256, 0, stream>>>(dst, bcnt, E, nbuck);
    scanA_kernel<<<1, 1024, 0, stream>>>(bcnt, boffs, bhead, nbuck);
    scatterA_kernel<<<(E + TILE - 1) / TILE, 1024, 0, stream>>>(src, dst, etype, bhead, sortedA, E, nbuck);
    passB_kernel<<<nbuck, 256, 0, stream>>>(sortedA, boffs, sorted, offs2, N * 8, E, nbuck);

    int n4 = N * D / 4;
    int cb = (2 * KTOT * D + n4 + 255) / 256;
    cast_kernel<<<cb, 256, 0, stream>>>(W1, lw1, W2, lw2, feats, Bt1, Bt2, hb0, n4);

    for (int layer = 0; layer < 2; ++layer) {
        const unsigned short* hin = layer ? hb1 : hb0;
        const unsigned short* Bt  = layer ? Bt2 : Bt1;
        const float* bias         = layer ? b2  : b1;
        for (int c0 = 0; c0 < N; c0 += ch) {
            int c1 = (c0 + ch < N) ? (c0 + ch) : N;
            int len = c1 - c0;
            int ab = (len * 8 + 15) / 16;   // one (node,rel) segment per 16-lane unit
            int gb = (len + 31) / 32;
            aggregate_kernel<<<ab, 256, 0, stream>>>(hin, offs2, sorted, ACC, c0, c1);
            gemm_kernel<<<gb, 256, 0, stream>>>(ACC, hin, Bt, bias, out, hb1, c0, c1, 1 - layer);
        }
    }
}